// Round 1
// baseline (1972.539 us; speedup 1.0000x reference)
//
#include <hip/hip_runtime.h>

typedef float f32x4 __attribute__((ext_vector_type(4)));
typedef int   i32x4 __attribute__((ext_vector_type(4)));
typedef short s16x8 __attribute__((ext_vector_type(8)));

#define VOCAB 256
#define EMB   128
#define HID   512
#define OUT_D 256
#define BATCH 64
#define SEQ   1024

__device__ __forceinline__ unsigned short f2bf(float f) {
  unsigned u = __builtin_bit_cast(unsigned, f);
  u += 0x7fffu + ((u >> 16) & 1u);
  return (unsigned short)(u >> 16);
}

// ---------------------------------------------------------------------------
// Prep 1: E2[v][c] = sum_e emb[v][e]*We[e][c] + bh[c]   (f32, 256x512)
// ---------------------------------------------------------------------------
__global__ void k_e2(const float* __restrict__ emb, const float* __restrict__ We,
                     const float* __restrict__ bh, float* __restrict__ E2)
{
  __shared__ float el[EMB];
  const int v = blockIdx.x, c = threadIdx.x;   // 512 threads
  if (c < EMB) el[c] = emb[v * EMB + c];
  __syncthreads();
  float s = bh[c];
  #pragma unroll
  for (int e = 0; e < EMB; ++e) s += el[e] * We[e * HID + c];
  E2[v * HID + c] = s;
}

// ---------------------------------------------------------------------------
// Prep 2: W_h -> int8 (x2048) packed as MFMA B-fragments for 16x16x64 i8.
// frag = (w*4+nt)*8+kt ; lane holds B[k=(lane>>4)*16+j][col=wcolbase+nt*16+(lane&15)]
// ---------------------------------------------------------------------------
__global__ void k_whfrag(const float* __restrict__ Wh, i32x4* __restrict__ WhF)
{
  const int g = blockIdx.x * 256 + threadIdx.x;   // 0..16383
  const int lane = g & 63, frag = g >> 6;         // frag 0..255
  const int kt = frag & 7, nt = (frag >> 3) & 3, w = frag >> 5;
  const int col = (w << 6) + (nt << 4) + (lane & 15);
  const int kb  = (kt << 6) + ((lane >> 4) << 4);
  int wd[4];
  #pragma unroll
  for (int q = 0; q < 4; ++q) {
    int b[4];
    #pragma unroll
    for (int j = 0; j < 4; ++j) {
      float s = Wh[(kb + q * 4 + j) * HID + col] * 2048.f;
      s = fminf(fmaxf(s, -127.f), 127.f);
      b[j] = __float2int_rn(s) & 255;
    }
    wd[q] = b[0] | (b[1] << 8) | (b[2] << 16) | (b[3] << 24);
  }
  i32x4 v = {wd[0], wd[1], wd[2], wd[3]};
  WhF[g] = v;
}

// ---------------------------------------------------------------------------
// Prep 3: W_o -> bf16 transposed: WoT[col][k]
// ---------------------------------------------------------------------------
__global__ void k_wot(const float* __restrict__ Wo, unsigned short* __restrict__ WoT)
{
  const int k = blockIdx.x;      // 512
  const int c = threadIdx.x;     // 256
  WoT[c * HID + k] = f2bf(Wo[k * OUT_D + c]);
}

// ---------------------------------------------------------------------------
// Scan: 4 workgroups x 512 threads; each wg owns 16 batch rows, runs the full
// 1024-step recurrence. W_h int8 fragments live in registers (128 VGPR/lane).
// h (int8, x127) double-buffered in swizzled LDS. hx gathered from E2 in f32.
// Writes h history as bf16 into `hist` (aliases d_out) and final h into fh.
// ---------------------------------------------------------------------------
__global__ __launch_bounds__(512, 2) void k_scan(
    const int* __restrict__ x, const float* __restrict__ h0,
    const float* __restrict__ E2, const i32x4* __restrict__ WhF,
    unsigned short* __restrict__ hist, float* __restrict__ fh)
{
  __shared__ __align__(16) char hbuf[2][16 * HID];   // 2 x 8KB int8 h
  const int tid  = threadIdx.x;
  const int wv   = tid >> 6, lane = tid & 63;
  const int lrow = lane & 15, lhi = lane >> 4;
  const int bbase = blockIdx.x << 4;
  const int colb  = wv << 6;

  // Load this wave's W_h B-fragments into registers (4 N-tiles x 8 K-tiles).
  i32x4 bfr[4][8];
  #pragma unroll
  for (int nt = 0; nt < 4; ++nt)
    #pragma unroll
    for (int kt = 0; kt < 8; ++kt)
      bfr[nt][kt] = WhF[((((wv << 2) + nt) << 3) + kt) * 64 + lane];

  // h0 -> int8 into hbuf[0] (swizzled 16B granules). 512 granules, 512 threads.
  {
    const int g = tid;
    const int row = g >> 5, off = (g & 31) << 4;
    const float* hp = h0 + ((bbase + row) << 9) + off;
    int wd[4];
    #pragma unroll
    for (int q = 0; q < 4; ++q) {
      int bb[4];
      #pragma unroll
      for (int j = 0; j < 4; ++j) {
        float s = fminf(fmaxf(hp[q * 4 + j] * 127.f, -127.f), 127.f);
        bb[j] = __float2int_rn(s) & 255;
      }
      wd[q] = bb[0] | (bb[1] << 8) | (bb[2] << 16) | (bb[3] << 24);
    }
    i32x4 v = {wd[0], wd[1], wd[2], wd[3]};
    *(i32x4*)(&hbuf[0][(row << 9) + (off ^ ((row & 7) << 4))]) = v;
  }
  __syncthreads();

  const float inv = 1.f / (127.f * 2048.f);
  for (int t = 0; t < SEQ; ++t) {
    const char* hb = hbuf[t & 1];
    char* hn = hbuf[(t + 1) & 1];

    // token ids for this lane's 4 batch rows, then f32 hx gather from E2
    int id[4];
    #pragma unroll
    for (int r = 0; r < 4; ++r) id[r] = x[((bbase + (lhi << 2) + r) << 10) + t];
    float hx[4][4];
    #pragma unroll
    for (int nt = 0; nt < 4; ++nt)
      #pragma unroll
      for (int r = 0; r < 4; ++r)
        hx[nt][r] = E2[(id[r] << 9) + colb + (nt << 4) + lrow];

    // h_prev @ W_h : int8 MFMA, exact i32 accumulation
    i32x4 acc[4] = {};
    #pragma unroll
    for (int kt = 0; kt < 8; ++kt) {
      i32x4 a = *(const i32x4*)(hb + (lrow << 9) +
                                (((kt << 6) + (lhi << 4)) ^ ((lrow & 7) << 4)));
      #pragma unroll
      for (int nt = 0; nt < 4; ++nt)
        acc[nt] = __builtin_amdgcn_mfma_i32_16x16x64_i8(a, bfr[nt][kt], acc[nt], 0, 0, 0);
    }

    // epilogue: z = acc/ (127*2048) + hx ; h = tanh(z)
    #pragma unroll
    for (int nt = 0; nt < 4; ++nt) {
      const int col = colb + (nt << 4) + lrow;
      #pragma unroll
      for (int r = 0; r < 4; ++r) {
        const int row = (lhi << 2) + r;
        float z = (float)acc[nt][r] * inv + hx[nt][r];
        float e = __builtin_amdgcn_exp2f(z * 2.8853900817779268f);  // 2*log2(e)
        float h = 1.f - 2.f * __builtin_amdgcn_rcpf(1.f + e);
        hist[((((bbase + row) << 10) + t) << 9) + col] = f2bf(h);
        hn[(row << 9) + (col ^ ((row & 7) << 4))] = (char)__float2int_rn(h * 127.f);
        if (t == SEQ - 1) fh[((bbase + row) << 9) + col] = h;
      }
    }
    __syncthreads();
  }
}

// ---------------------------------------------------------------------------
// Logits: [65536,512]bf16 @ [512,256]bf16 + b_o, in-place over d_out.
// Each block: 64 M-rows staged to LDS (swizzled), 4 waves x 64 N-cols.
// ---------------------------------------------------------------------------
__global__ __launch_bounds__(256) void k_logits(const unsigned short* hist,
                                                const unsigned short* __restrict__ WoT,
                                                const float* __restrict__ bo, float* out)
{
  __shared__ __align__(16) char As[64 * 1024];
  const int tid = threadIdx.x;
  const int m0 = blockIdx.x * 64;

  // stage A tile (64 rows x 512 bf16) with XOR swizzle on 16B granules
  for (int i = tid; i < 64 * 64; i += 256) {
    const int row = i >> 6, g = i & 63;
    i32x4 v = *(const i32x4*)((const char*)hist + (size_t)(m0 + row) * 1024 + g * 16);
    *(i32x4*)(&As[row * 1024 + ((g * 16) ^ ((row & 7) << 4))]) = v;
  }
  __syncthreads();

  const int wv = tid >> 6, lane = tid & 63, lrow = lane & 15, lhi = lane >> 4;
  const int cb = wv << 6;
  f32x4 acc[4][4] = {};
  #pragma unroll
  for (int kt = 0; kt < 16; ++kt) {
    s16x8 a[4], b[4];
    #pragma unroll
    for (int mt = 0; mt < 4; ++mt) {
      const int row = mt * 16 + lrow;
      a[mt] = *(const s16x8*)(&As[row * 1024 + ((kt * 64 + lhi * 16) ^ ((row & 7) << 4))]);
    }
    #pragma unroll
    for (int nt = 0; nt < 4; ++nt) {
      const int col = cb + nt * 16 + lrow;
      b[nt] = *(const s16x8*)((const char*)WoT + col * 1024 + kt * 64 + lhi * 16);
    }
    #pragma unroll
    for (int mt = 0; mt < 4; ++mt)
      #pragma unroll
      for (int nt = 0; nt < 4; ++nt)
        acc[mt][nt] = __builtin_amdgcn_mfma_f32_16x16x32_bf16(a[mt], b[nt], acc[mt][nt], 0, 0, 0);
  }
  #pragma unroll
  for (int nt = 0; nt < 4; ++nt) {
    const float bb = bo[cb + nt * 16 + lrow];
    #pragma unroll
    for (int mt = 0; mt < 4; ++mt)
      #pragma unroll
      for (int r = 0; r < 4; ++r)
        out[(size_t)(m0 + mt * 16 + lhi * 4 + r) * OUT_D + cb + nt * 16 + lrow] =
            acc[mt][nt][r] + bb;
  }
}

// ---------------------------------------------------------------------------
extern "C" void kernel_launch(void* const* d_in, const int* in_sizes, int n_in,
                              void* d_out, int out_size, void* d_ws, size_t ws_size,
                              hipStream_t stream)
{
  const int*   x   = (const int*)  d_in[0];
  const float* h0  = (const float*)d_in[1];
  const float* emb = (const float*)d_in[2];
  const float* We  = (const float*)d_in[3];
  const float* Wh  = (const float*)d_in[4];
  const float* bh  = (const float*)d_in[5];
  const float* Wo  = (const float*)d_in[6];
  const float* bo  = (const float*)d_in[7];
  float* out = (float*)d_out;
  char*  ws  = (char*)d_ws;

  float*          E2  = (float*)ws;                              // 512 KB
  i32x4*          WhF = (i32x4*)(ws + (512 << 10));              // 256 KB
  unsigned short* WoT = (unsigned short*)(ws + (768 << 10));     // 256 KB

  k_e2    <<<VOCAB, HID,   0, stream>>>(emb, We, bh, E2);
  k_whfrag<<<64,    256,   0, stream>>>(Wh, WhF);
  k_wot   <<<HID,   OUT_D, 0, stream>>>(Wo, WoT);

  // h history (bf16) is written into d_out itself; logits GEMM then runs
  // in-place (per-64-row tiles staged to LDS before being overwritten).
  k_scan  <<<4, 512, 0, stream>>>(x, h0, E2, WhF,
                                  (unsigned short*)d_out,
                                  out + (size_t)BATCH * SEQ * OUT_D);
  k_logits<<<(BATCH * SEQ) / 64, 256, 0, stream>>>(
      (const unsigned short*)d_out, WoT, bo, out);
}

// Round 2
// 1673.863 us; speedup vs baseline: 1.1784x; 1.1784x over previous
//
#include <hip/hip_runtime.h>

typedef float f32x4 __attribute__((ext_vector_type(4)));
typedef int   i32x4 __attribute__((ext_vector_type(4)));
typedef short s16x8 __attribute__((ext_vector_type(8)));

#define VOCAB 256
#define EMB   128
#define HID   512
#define OUT_D 256
#define BATCH 64
#define SEQ   1024

__device__ __forceinline__ unsigned short f2bf(float f) {
  unsigned u = __builtin_bit_cast(unsigned, f);
  u += 0x7fffu + ((u >> 16) & 1u);
  return (unsigned short)(u >> 16);
}

// ---------------------------------------------------------------------------
// Prep 1: E2[v][c] = sum_e emb[v][e]*We[e][c] + bh[c]   (f32, 256x512)
// ---------------------------------------------------------------------------
__global__ void k_e2(const float* __restrict__ emb, const float* __restrict__ We,
                     const float* __restrict__ bh, float* __restrict__ E2)
{
  __shared__ float el[EMB];
  const int v = blockIdx.x, c = threadIdx.x;   // 512 threads
  if (c < EMB) el[c] = emb[v * EMB + c];
  __syncthreads();
  float s = bh[c];
  #pragma unroll
  for (int e = 0; e < EMB; ++e) s += el[e] * We[e * HID + c];
  E2[v * HID + c] = s;
}

// ---------------------------------------------------------------------------
// Prep 2: W_h -> int8 (x2048) packed as MFMA B-fragments for 16x16x64 i8.
// ---------------------------------------------------------------------------
__global__ void k_whfrag(const float* __restrict__ Wh, i32x4* __restrict__ WhF)
{
  const int g = blockIdx.x * 256 + threadIdx.x;   // 0..16383
  const int lane = g & 63, frag = g >> 6;         // frag 0..255
  const int kt = frag & 7, nt = (frag >> 3) & 3, w = frag >> 5;
  const int col = (w << 6) + (nt << 4) + (lane & 15);
  const int kb  = (kt << 6) + ((lane >> 4) << 4);
  int wd[4];
  #pragma unroll
  for (int q = 0; q < 4; ++q) {
    int b[4];
    #pragma unroll
    for (int j = 0; j < 4; ++j) {
      float s = Wh[(kb + q * 4 + j) * HID + col] * 2048.f;
      s = fminf(fmaxf(s, -127.f), 127.f);
      b[j] = __float2int_rn(s) & 255;
    }
    wd[q] = b[0] | (b[1] << 8) | (b[2] << 16) | (b[3] << 24);
  }
  i32x4 v = {wd[0], wd[1], wd[2], wd[3]};
  WhF[g] = v;
}

// ---------------------------------------------------------------------------
// Prep 3: W_o -> bf16 transposed: WoT[col][k]
// ---------------------------------------------------------------------------
__global__ void k_wot(const float* __restrict__ Wo, unsigned short* __restrict__ WoT)
{
  const int k = blockIdx.x;      // 512
  const int c = threadIdx.x;     // 256
  WoT[c * HID + k] = f2bf(Wo[k * OUT_D + c]);
}

// ---------------------------------------------------------------------------
// Scan: 4 WGs x 512 thr; each owns 16 batch rows, full 1024-step recurrence.
// W_h int8 frags in AGPRs; h int8 double-buffered in swizzled LDS; x/E2
// gathers software-pipelined 2/1 steps ahead; bf16 h-history staged in LDS
// and flushed coalesced; raw s_barrier (no vmcnt drain) per step.
// ---------------------------------------------------------------------------
__global__ __launch_bounds__(512, 2) void k_scan(
    const int* __restrict__ x, const float* __restrict__ h0,
    const float* __restrict__ E2, const i32x4* __restrict__ WhF,
    unsigned short* __restrict__ hist, float* __restrict__ fh)
{
  __shared__ __align__(16) char hbuf[2][16 * HID];            // 2 x 8KB int8 h
  __shared__ __align__(16) unsigned short histL[2][16 * HID]; // 2 x 16KB bf16 h
  const int tid  = threadIdx.x;
  const int wv   = tid >> 6, lane = tid & 63;
  const int lrow = lane & 15, lhi = lane >> 4;
  const int bbase = blockIdx.x << 4;
  const int colb  = wv << 6;

  // W_h B-fragments -> registers (compiler places in AGPRs; MFMA reads direct)
  i32x4 bfr[4][8];
  #pragma unroll
  for (int nt = 0; nt < 4; ++nt)
    #pragma unroll
    for (int kt = 0; kt < 8; ++kt)
      bfr[nt][kt] = WhF[((((wv << 2) + nt) << 3) + kt) * 64 + lane];

  // ---- loop-invariant addresses (XOR swizzle folded into bases) ----
  // A-frag reads: addr(kt) = (kt even ? abase_e : abase_o) + 128*(kt>>1)
  const int f_ = (lrow >> 2) & 1;
  const int abase_e = lrow * 512 + 16 * (lhi ^ (lrow & 3)) + 64 * f_;
  const int abase_o = abase_e ^ 64;
  // hn int8 writes: addr(nt,r) = nbase[r] + 16*(nt^r)
  int nbase[4];
  #pragma unroll
  for (int r = 0; r < 4; ++r)
    nbase[r] = (lhi * 4 + r) * 512 + lrow + 64 * ((wv & 1) ^ (lhi & 1)) +
               128 * (wv >> 1);
  // hist bf16 staging (unswizzled [row][col]): addr = hbase + r*1024 + nt*32
  const int hbase = lhi * 4096 + (colb + lrow) * 2;
  // flush: each thread stores 2 x 16B granules
  const int frow = tid >> 6, fc = (tid & 63) * 16;
  const int flds = frow * 1024 + fc;                              // + 8192 for g2
  const unsigned fg1 = ((unsigned)(bbase + frow) << 20) + (unsigned)fc;
  const unsigned fg2 = ((unsigned)(bbase + frow + 8) << 20) + (unsigned)fc;

  // ---- prologue: ids for t=0 (wait) and t=1; hx for t=0; h0 -> hbuf[0] ----
  int idA[4], idB[4];
  int id0[4];
  #pragma unroll
  for (int r = 0; r < 4; ++r) id0[r] = x[((bbase + lhi * 4 + r) << 10) + 0];
  #pragma unroll
  for (int r = 0; r < 4; ++r) idA[r] = x[((bbase + lhi * 4 + r) << 10) + 1];
  float hxA[16], hxB[16];
  #pragma unroll
  for (int r = 0; r < 4; ++r) {
    const int e2o = (id0[r] << 9) + colb + lrow;
    #pragma unroll
    for (int nt = 0; nt < 4; ++nt) hxA[nt * 4 + r] = E2[e2o + nt * 16];
  }
  {
    const int g = tid;
    const int row = g >> 5, off = (g & 31) << 4;
    const float* hp = h0 + ((bbase + row) << 9) + off;
    int wd[4];
    #pragma unroll
    for (int q = 0; q < 4; ++q) {
      int bb[4];
      #pragma unroll
      for (int j = 0; j < 4; ++j) {
        float s = fminf(fmaxf(hp[q * 4 + j] * 127.f, -127.f), 127.f);
        bb[j] = __float2int_rn(s) & 255;
      }
      wd[q] = bb[0] | (bb[1] << 8) | (bb[2] << 16) | (bb[3] << 24);
    }
    i32x4 v = {wd[0], wd[1], wd[2], wd[3]};
    *(i32x4*)(&hbuf[0][(row << 9) + (off ^ ((row & 7) << 4))]) = v;
  }
  __syncthreads();

  const float inv = 1.f / (127.f * 2048.f);
  const float TC  = 2.8853900817779268f;   // 2*log2(e)

#define STEP(T, PH, HXU, HXP, IDU, IDL)                                       \
  {                                                                           \
    const int t_ = (T);                                                       \
    /* coalesced flush of previous step's bf16 tile (no drain needed) */      \
    if (t_ > 0) {                                                             \
      const char* hs = (const char*)histL[1 - (PH)];                          \
      i32x4 v0 = *(const i32x4*)(hs + flds);                                  \
      i32x4 v1 = *(const i32x4*)(hs + flds + 8192);                           \
      const unsigned tb = (unsigned)(t_ - 1) << 10;                           \
      *(i32x4*)((char*)hist + (fg1 + tb)) = v0;                               \
      *(i32x4*)((char*)hist + (fg2 + tb)) = v1;                               \
    }                                                                         \
    /* prefetch E2 rows for t+1 (ids fetched one step earlier) */             \
    _Pragma("unroll") for (int r = 0; r < 4; ++r) {                           \
      const int e2o = (IDU[r] << 9) + colb + lrow;                            \
      _Pragma("unroll") for (int nt = 0; nt < 4; ++nt)                        \
        HXP[nt * 4 + r] = E2[e2o + nt * 16];                                  \
    }                                                                         \
    /* prefetch token ids for t+2 */                                          \
    {                                                                         \
      const int tc = (t_ + 2 > SEQ - 1) ? SEQ - 1 : t_ + 2;                   \
      _Pragma("unroll") for (int r = 0; r < 4; ++r)                           \
        IDL[r] = x[((bbase + lhi * 4 + r) << 10) + tc];                       \
    }                                                                         \
    /* h_prev @ W_h : int8 MFMA, exact i32 accumulation */                    \
    i32x4 acc[4] = {};                                                        \
    _Pragma("unroll") for (int kt = 0; kt < 8; ++kt) {                        \
      const int aoff = ((kt & 1) ? abase_o : abase_e) + 128 * (kt >> 1);      \
      i32x4 a = *(const i32x4*)(&hbuf[PH][0] + aoff);                         \
      _Pragma("unroll") for (int nt = 0; nt < 4; ++nt)                        \
        acc[nt] = __builtin_amdgcn_mfma_i32_16x16x64_i8(a, bfr[nt][kt],       \
                                                        acc[nt], 0, 0, 0);    \
    }                                                                         \
    /* epilogue: z = acc*inv + hx ; h = tanh(z) ; emit bf16 + int8 */         \
    _Pragma("unroll") for (int nt = 0; nt < 4; ++nt) {                        \
      _Pragma("unroll") for (int r = 0; r < 4; ++r) {                         \
        float z = fmaf((float)acc[nt][r], inv, HXU[nt * 4 + r]);              \
        float e = __builtin_amdgcn_exp2f(z * TC);                             \
        float h = fmaf(-2.f, __builtin_amdgcn_rcpf(1.f + e), 1.f);            \
        *(unsigned short*)((char*)histL[PH] + hbase + r * 1024 + nt * 32) =   \
            f2bf(h);                                                          \
        *(char*)(&hbuf[1 - (PH)][0] + nbase[r] + 16 * ((nt) ^ (r))) =         \
            (char)__float2int_rn(h * 127.f);                                  \
        if (t_ == SEQ - 1)                                                    \
          fh[((bbase + lhi * 4 + r) << 9) + colb + nt * 16 + lrow] = h;       \
      }                                                                       \
    }                                                                         \
    asm volatile("s_waitcnt lgkmcnt(0)" ::: "memory");                        \
    __builtin_amdgcn_sched_barrier(0);                                        \
    __builtin_amdgcn_s_barrier();                                             \
    __builtin_amdgcn_sched_barrier(0);                                        \
  }

  for (int T2 = 0; T2 < SEQ / 2; ++T2) {
    STEP(2 * T2,     0, hxA, hxB, idA, idB)
    STEP(2 * T2 + 1, 1, hxB, hxA, idB, idA)
  }
#undef STEP

  // final flush: t = 1023 tile lives in histL[1]
  {
    const char* hs = (const char*)histL[1];
    i32x4 v0 = *(const i32x4*)(hs + flds);
    i32x4 v1 = *(const i32x4*)(hs + flds + 8192);
    const unsigned tb = (unsigned)(SEQ - 1) << 10;
    *(i32x4*)((char*)hist + (fg1 + tb)) = v0;
    *(i32x4*)((char*)hist + (fg2 + tb)) = v1;
  }
}

// ---------------------------------------------------------------------------
// Logits: [65536,512]bf16 @ [512,256]bf16 + b_o, in-place over d_out.
// ---------------------------------------------------------------------------
__global__ __launch_bounds__(256) void k_logits(const unsigned short* hist,
                                                const unsigned short* __restrict__ WoT,
                                                const float* __restrict__ bo, float* out)
{
  __shared__ __align__(16) char As[64 * 1024];
  const int tid = threadIdx.x;
  const int m0 = blockIdx.x * 64;

  for (int i = tid; i < 64 * 64; i += 256) {
    const int row = i >> 6, g = i & 63;
    i32x4 v = *(const i32x4*)((const char*)hist + (size_t)(m0 + row) * 1024 + g * 16);
    *(i32x4*)(&As[row * 1024 + ((g * 16) ^ ((row & 7) << 4))]) = v;
  }
  __syncthreads();

  const int wv = tid >> 6, lane = tid & 63, lrow = lane & 15, lhi = lane >> 4;
  const int cb = wv << 6;
  f32x4 acc[4][4] = {};
  #pragma unroll
  for (int kt = 0; kt < 16; ++kt) {
    s16x8 a[4], b[4];
    #pragma unroll
    for (int mt = 0; mt < 4; ++mt) {
      const int row = mt * 16 + lrow;
      a[mt] = *(const s16x8*)(&As[row * 1024 + ((kt * 64 + lhi * 16) ^ ((row & 7) << 4))]);
    }
    #pragma unroll
    for (int nt = 0; nt < 4; ++nt) {
      const int col = cb + nt * 16 + lrow;
      b[nt] = *(const s16x8*)((const char*)WoT + col * 1024 + kt * 64 + lhi * 16);
    }
    #pragma unroll
    for (int mt = 0; mt < 4; ++mt)
      #pragma unroll
      for (int nt = 0; nt < 4; ++nt)
        acc[mt][nt] = __builtin_amdgcn_mfma_f32_16x16x32_bf16(a[mt], b[nt], acc[mt][nt], 0, 0, 0);
  }
  #pragma unroll
  for (int nt = 0; nt < 4; ++nt) {
    const float bb = bo[cb + nt * 16 + lrow];
    #pragma unroll
    for (int mt = 0; mt < 4; ++mt)
      #pragma unroll
      for (int r = 0; r < 4; ++r)
        out[(size_t)(m0 + mt * 16 + lhi * 4 + r) * OUT_D + cb + nt * 16 + lrow] =
            acc[mt][nt][r] + bb;
  }
}

// ---------------------------------------------------------------------------
extern "C" void kernel_launch(void* const* d_in, const int* in_sizes, int n_in,
                              void* d_out, int out_size, void* d_ws, size_t ws_size,
                              hipStream_t stream)
{
  const int*   x   = (const int*)  d_in[0];
  const float* h0  = (const float*)d_in[1];
  const float* emb = (const float*)d_in[2];
  const float* We  = (const float*)d_in[3];
  const float* Wh  = (const float*)d_in[4];
  const float* bh  = (const float*)d_in[5];
  const float* Wo  = (const float*)d_in[6];
  const float* bo  = (const float*)d_in[7];
  float* out = (float*)d_out;
  char*  ws  = (char*)d_ws;

  float*          E2  = (float*)ws;                              // 512 KB
  i32x4*          WhF = (i32x4*)(ws + (512 << 10));              // 256 KB
  unsigned short* WoT = (unsigned short*)(ws + (768 << 10));     // 256 KB

  k_e2    <<<VOCAB, HID,   0, stream>>>(emb, We, bh, E2);
  k_whfrag<<<64,    256,   0, stream>>>(Wh, WhF);
  k_wot   <<<HID,   OUT_D, 0, stream>>>(Wo, WoT);

  k_scan  <<<4, 512, 0, stream>>>(x, h0, E2, WhF,
                                  (unsigned short*)d_out,
                                  out + (size_t)BATCH * SEQ * OUT_D);
  k_logits<<<(BATCH * SEQ) / 64, 256, 0, stream>>>(
      (const unsigned short*)d_out, WoT, bo, out);
}

// Round 3
// 1439.240 us; speedup vs baseline: 1.3705x; 1.1630x over previous
//
#include <hip/hip_runtime.h>

typedef float f32x4 __attribute__((ext_vector_type(4)));
typedef int   i32x4 __attribute__((ext_vector_type(4)));
typedef short s16x8 __attribute__((ext_vector_type(8)));

#define VOCAB 256
#define EMB   128
#define HID   512
#define OUT_D 256
#define BATCH 64
#define SEQ   1024

__device__ __forceinline__ unsigned short f2bf(float f) {
  unsigned u = __builtin_bit_cast(unsigned, f);
  u += 0x7fffu + ((u >> 16) & 1u);
  return (unsigned short)(u >> 16);
}

// ---------------------------------------------------------------------------
// Prep 1: E2[v][c] = sum_e emb[v][e]*We[e][c] + bh[c]   (f32, 256x512)
// ---------------------------------------------------------------------------
__global__ void k_e2(const float* __restrict__ emb, const float* __restrict__ We,
                     const float* __restrict__ bh, float* __restrict__ E2)
{
  __shared__ float el[EMB];
  const int v = blockIdx.x, c = threadIdx.x;   // 512 threads
  if (c < EMB) el[c] = emb[v * EMB + c];
  __syncthreads();
  float s = bh[c];
  #pragma unroll
  for (int e = 0; e < EMB; ++e) s += el[e] * We[e * HID + c];
  E2[v * HID + c] = s;
}

// ---------------------------------------------------------------------------
// Prep 2: W_h -> int8 (x2048) packed as MFMA B-fragments for 16x16x64 i8.
// ---------------------------------------------------------------------------
__global__ void k_whfrag(const float* __restrict__ Wh, i32x4* __restrict__ WhF)
{
  const int g = blockIdx.x * 256 + threadIdx.x;   // 0..16383
  const int lane = g & 63, frag = g >> 6;         // frag 0..255
  const int kt = frag & 7, nt = (frag >> 3) & 3, w = frag >> 5;
  const int col = (w << 6) + (nt << 4) + (lane & 15);
  const int kb  = (kt << 6) + ((lane >> 4) << 4);
  int wd[4];
  #pragma unroll
  for (int q = 0; q < 4; ++q) {
    int b[4];
    #pragma unroll
    for (int j = 0; j < 4; ++j) {
      float s = Wh[(kb + q * 4 + j) * HID + col] * 2048.f;
      s = fminf(fmaxf(s, -127.f), 127.f);
      b[j] = __float2int_rn(s) & 255;
    }
    wd[q] = b[0] | (b[1] << 8) | (b[2] << 16) | (b[3] << 24);
  }
  i32x4 v = {wd[0], wd[1], wd[2], wd[3]};
  WhF[g] = v;
}

// ---------------------------------------------------------------------------
// Prep 3: W_o -> bf16 transposed AND pre-scaled by 1/127 (hist is int8 x127):
// WoT[col][k] = bf16(Wo[k][col] / 127)
// ---------------------------------------------------------------------------
__global__ void k_wot(const float* __restrict__ Wo, unsigned short* __restrict__ WoT)
{
  const int k = blockIdx.x;      // 512
  const int c = threadIdx.x;     // 256
  WoT[c * HID + k] = f2bf(Wo[k * OUT_D + c] * (1.0f / 127.0f));
}

// ---------------------------------------------------------------------------
// Scan: 4 WGs x 512 thr; each owns 16 batch rows, full 1024-step recurrence.
// W_h int8 frags in AGPRs; h int8 double-buffered in swizzled LDS. The int8
// state buffer IS the history: each step the stable A-source buffer is
// unswizzle-read (1 ds_read_b128/lane) and stored coalesced (1 dwordx4/lane)
// into the 512B prefix of the matching logits row of d_out. No bf16 staging.
// ---------------------------------------------------------------------------
__global__ __launch_bounds__(512, 2) void k_scan(
    const int* __restrict__ x, const float* __restrict__ h0,
    const float* __restrict__ E2, const i32x4* __restrict__ WhF,
    char* __restrict__ hist, float* __restrict__ fh)
{
  __shared__ __align__(16) char hbuf[2][16 * HID];   // 2 x 8KB int8 h
  const int tid  = threadIdx.x;
  const int wv   = tid >> 6, lane = tid & 63;
  const int lrow = lane & 15, lhi = lane >> 4;
  const int bbase = blockIdx.x << 4;
  const int colb  = wv << 6;

  // W_h B-fragments -> registers (AGPRs; MFMA reads direct)
  i32x4 bfr[4][8];
  #pragma unroll
  for (int nt = 0; nt < 4; ++nt)
    #pragma unroll
    for (int kt = 0; kt < 8; ++kt)
      bfr[nt][kt] = WhF[((((wv << 2) + nt) << 3) + kt) * 64 + lane];

  // ---- loop-invariant addresses (XOR swizzle folded into bases) ----
  // A-frag reads: addr(kt) = (kt even ? abase_e : abase_o) + 128*(kt>>1)
  const int f_ = (lrow >> 2) & 1;
  const int abase_e = lrow * 512 + 16 * (lhi ^ (lrow & 3)) + 64 * f_;
  const int abase_o = abase_e ^ 64;
  // hn int8 writes: addr(nt,r) = nbase[r] + 16*(nt^r)
  int nbase[4];
  #pragma unroll
  for (int r = 0; r < 4; ++r)
    nbase[r] = (lhi * 4 + r) * 512 + lrow + 64 * ((wv & 1) ^ (lhi & 1)) +
               128 * (wv >> 1);
  // history flush: thread covers 16B granule (frow, fcg) of the A-source buf
  const int frow = tid >> 5;                         // 0..15
  const int fcg  = (tid & 31) << 4;                  // 0..496
  const int flds = frow * 512 + (fcg ^ ((frow & 7) << 4));
  char* const fgp = hist + ((size_t)(bbase + frow) << 20) + fcg;

  // ---- prologue: ids for t=0 (wait) and t=1; hx for t=0; h0 -> hbuf[0] ----
  int idA[4], idB[4];
  int id0[4];
  #pragma unroll
  for (int r = 0; r < 4; ++r) id0[r] = x[((bbase + lhi * 4 + r) << 10) + 0];
  #pragma unroll
  for (int r = 0; r < 4; ++r) idA[r] = x[((bbase + lhi * 4 + r) << 10) + 1];
  float hxA[16], hxB[16];
  #pragma unroll
  for (int r = 0; r < 4; ++r) {
    const int e2o = (id0[r] << 9) + colb + lrow;
    #pragma unroll
    for (int nt = 0; nt < 4; ++nt) hxA[nt * 4 + r] = E2[e2o + nt * 16];
  }
  {
    const int g = tid;
    const int row = g >> 5, off = (g & 31) << 4;
    const float* hp = h0 + ((bbase + row) << 9) + off;
    int wd[4];
    #pragma unroll
    for (int q = 0; q < 4; ++q) {
      int bb[4];
      #pragma unroll
      for (int j = 0; j < 4; ++j) {
        float s = fminf(fmaxf(hp[q * 4 + j] * 127.f, -127.f), 127.f);
        bb[j] = __float2int_rn(s) & 255;
      }
      wd[q] = bb[0] | (bb[1] << 8) | (bb[2] << 16) | (bb[3] << 24);
    }
    i32x4 v = {wd[0], wd[1], wd[2], wd[3]};
    *(i32x4*)(&hbuf[0][(row << 9) + (off ^ ((row & 7) << 4))]) = v;
  }
  __syncthreads();

  const float inv = 1.f / (127.f * 2048.f);
  const float TC  = 2.8853900817779268f;   // 2*log2(e)

#define STEP(T, PH, HXU, HXP, IDU, IDL)                                       \
  {                                                                           \
    const int t_ = (T);                                                       \
    /* history flush read: hbuf[PH] = outputs[t-1], stable this step */       \
    i32x4 fv = *(const i32x4*)(&hbuf[PH][0] + flds);                          \
    /* prefetch E2 rows for t+1 (ids fetched one step earlier) */             \
    _Pragma("unroll") for (int r = 0; r < 4; ++r) {                           \
      const int e2o = (IDU[r] << 9) + colb + lrow;                            \
      _Pragma("unroll") for (int nt = 0; nt < 4; ++nt)                        \
        HXP[nt * 4 + r] = E2[e2o + nt * 16];                                  \
    }                                                                         \
    /* prefetch token ids for t+2 */                                          \
    {                                                                         \
      const int tc = (t_ + 2 > SEQ - 1) ? SEQ - 1 : t_ + 2;                   \
      _Pragma("unroll") for (int r = 0; r < 4; ++r)                           \
        IDL[r] = x[((bbase + lhi * 4 + r) << 10) + tc];                       \
    }                                                                         \
    /* h_prev @ W_h : int8 MFMA, exact i32 accumulation */                    \
    i32x4 acc[4] = {};                                                        \
    _Pragma("unroll") for (int kt = 0; kt < 8; ++kt) {                        \
      const int aoff = ((kt & 1) ? abase_o : abase_e) + 128 * (kt >> 1);      \
      i32x4 a = *(const i32x4*)(&hbuf[PH][0] + aoff);                         \
      _Pragma("unroll") for (int nt = 0; nt < 4; ++nt)                        \
        acc[nt] = __builtin_amdgcn_mfma_i32_16x16x64_i8(a, bfr[nt][kt],       \
                                                        acc[nt], 0, 0, 0);    \
    }                                                                         \
    /* history flush store (ds_read long complete; store is coalesced) */     \
    if (t_ > 0) *(i32x4*)(fgp + ((unsigned)(t_ - 1) << 10)) = fv;             \
    /* epilogue: z = acc*inv + hx ; h = tanh(z) ; emit int8 */                \
    _Pragma("unroll") for (int nt = 0; nt < 4; ++nt) {                        \
      _Pragma("unroll") for (int r = 0; r < 4; ++r) {                         \
        float z = fmaf((float)acc[nt][r], inv, HXU[nt * 4 + r]);              \
        float e = __builtin_amdgcn_exp2f(z * TC);                             \
        float h = fmaf(-2.f, __builtin_amdgcn_rcpf(1.f + e), 1.f);            \
        *(char*)(&hbuf[1 - (PH)][0] + nbase[r] + 16 * ((nt) ^ (r))) =         \
            (char)__float2int_rn(h * 127.f);                                  \
        if (t_ == SEQ - 1)                                                    \
          fh[((bbase + lhi * 4 + r) << 9) + colb + nt * 16 + lrow] = h;       \
      }                                                                       \
    }                                                                         \
    asm volatile("s_waitcnt lgkmcnt(0)" ::: "memory");                        \
    __builtin_amdgcn_sched_barrier(0);                                        \
    __builtin_amdgcn_s_barrier();                                             \
    __builtin_amdgcn_sched_barrier(0);                                        \
  }

  for (int T2 = 0; T2 < SEQ / 2; ++T2) {
    STEP(2 * T2,     0, hxA, hxB, idA, idB)
    STEP(2 * T2 + 1, 1, hxB, hxA, idB, idA)
  }
#undef STEP

  // final flush: outputs[1023] lives in hbuf[0] (written by step 1023)
  {
    i32x4 fv = *(const i32x4*)(&hbuf[0][0] + flds);
    *(i32x4*)(fgp + ((unsigned)(SEQ - 1) << 10)) = fv;
  }
}

// ---------------------------------------------------------------------------
// Logits: A = int8 hist (512B prefix of each 1024B row slot) dequantized to
// bf16 during LDS staging (exact: |q|<=127 ints are exact bf16; 1/127 folded
// into WoT). GEMM in-place over d_out as before.
// ---------------------------------------------------------------------------
__global__ __launch_bounds__(256) void k_logits(const char* __restrict__ hist,
                                                const unsigned short* __restrict__ WoT,
                                                const float* __restrict__ bo, float* out)
{
  __shared__ __align__(16) char As[64 * 1024];
  const int tid = threadIdx.x;
  const int m0 = blockIdx.x * 64;

  // stage + dequant: 64 rows x 512 int8 -> bf16 tile with 16B-granule swizzle
  for (int i = tid; i < 1024; i += 256) {
    const int row = i >> 4, seg = i & 15;                 // 32 int8 cols/seg
    const char* src = hist + (size_t)(m0 + row) * 1024 + seg * 32;
    i32x4 w0 = *(const i32x4*)(src);
    i32x4 w1 = *(const i32x4*)(src + 16);
    unsigned od[16];
    #pragma unroll
    for (int d = 0; d < 8; ++d) {
      const unsigned dw = (unsigned)(d < 4 ? w0[d] : w1[d - 4]);
      const int q0 = (int)(signed char)(dw & 0xffu);
      const int q1 = (int)(signed char)((dw >> 8) & 0xffu);
      const int q2 = (int)(signed char)((dw >> 16) & 0xffu);
      const int q3 = (int)(signed char)(dw >> 24);
      const unsigned u0 = __builtin_bit_cast(unsigned, (float)q0);
      const unsigned u1 = __builtin_bit_cast(unsigned, (float)q1);
      const unsigned u2 = __builtin_bit_cast(unsigned, (float)q2);
      const unsigned u3 = __builtin_bit_cast(unsigned, (float)q3);
      od[2 * d]     = (u0 >> 16) | (u1 & 0xffff0000u);
      od[2 * d + 1] = (u2 >> 16) | (u3 & 0xffff0000u);
    }
    #pragma unroll
    for (int q = 0; q < 4; ++q) {
      i32x4 v = {(int)od[4 * q], (int)od[4 * q + 1],
                 (int)od[4 * q + 2], (int)od[4 * q + 3]};
      const int off = seg * 64 + q * 16;
      *(i32x4*)(&As[row * 1024 + (off ^ ((row & 7) << 4))]) = v;
    }
  }
  __syncthreads();

  const int wv = tid >> 6, lane = tid & 63, lrow = lane & 15, lhi = lane >> 4;
  const int cb = wv << 6;
  f32x4 acc[4][4] = {};
  #pragma unroll
  for (int kt = 0; kt < 16; ++kt) {
    s16x8 a[4], b[4];
    #pragma unroll
    for (int mt = 0; mt < 4; ++mt) {
      const int row = mt * 16 + lrow;
      a[mt] = *(const s16x8*)(&As[row * 1024 + ((kt * 64 + lhi * 16) ^ ((row & 7) << 4))]);
    }
    #pragma unroll
    for (int nt = 0; nt < 4; ++nt) {
      const int col = cb + nt * 16 + lrow;
      b[nt] = *(const s16x8*)((const char*)WoT + col * 1024 + kt * 64 + lhi * 16);
    }
    #pragma unroll
    for (int mt = 0; mt < 4; ++mt)
      #pragma unroll
      for (int nt = 0; nt < 4; ++nt)
        acc[mt][nt] = __builtin_amdgcn_mfma_f32_16x16x32_bf16(a[mt], b[nt], acc[mt][nt], 0, 0, 0);
  }
  #pragma unroll
  for (int nt = 0; nt < 4; ++nt) {
    const float bb = bo[cb + nt * 16 + lrow];
    #pragma unroll
    for (int mt = 0; mt < 4; ++mt)
      #pragma unroll
      for (int r = 0; r < 4; ++r)
        out[(size_t)(m0 + mt * 16 + lhi * 4 + r) * OUT_D + cb + nt * 16 + lrow] =
            acc[mt][nt][r] + bb;
  }
}

// ---------------------------------------------------------------------------
extern "C" void kernel_launch(void* const* d_in, const int* in_sizes, int n_in,
                              void* d_out, int out_size, void* d_ws, size_t ws_size,
                              hipStream_t stream)
{
  const int*   x   = (const int*)  d_in[0];
  const float* h0  = (const float*)d_in[1];
  const float* emb = (const float*)d_in[2];
  const float* We  = (const float*)d_in[3];
  const float* Wh  = (const float*)d_in[4];
  const float* bh  = (const float*)d_in[5];
  const float* Wo  = (const float*)d_in[6];
  const float* bo  = (const float*)d_in[7];
  float* out = (float*)d_out;
  char*  ws  = (char*)d_ws;

  float*          E2  = (float*)ws;                              // 512 KB
  i32x4*          WhF = (i32x4*)(ws + (512 << 10));              // 256 KB
  unsigned short* WoT = (unsigned short*)(ws + (768 << 10));     // 256 KB

  k_e2    <<<VOCAB, HID,   0, stream>>>(emb, We, bh, E2);
  k_whfrag<<<64,    256,   0, stream>>>(Wh, WhF);
  k_wot   <<<HID,   OUT_D, 0, stream>>>(Wo, WoT);

  // int8 h history lives in the 512B prefix of each logits row of d_out;
  // k_logits then overwrites each row in-place after staging it to LDS.
  k_scan  <<<4, 512, 0, stream>>>(x, h0, E2, WhF,
                                  (char*)d_out,
                                  out + (size_t)BATCH * SEQ * OUT_D);
  k_logits<<<(BATCH * SEQ) / 64, 256, 0, stream>>>(
      (const char*)d_out, WoT, bo, out);
}

// Round 4
// 734.819 us; speedup vs baseline: 2.6844x; 1.9586x over previous
//
#include <hip/hip_runtime.h>

typedef float f32x4 __attribute__((ext_vector_type(4)));
typedef int   i32x4 __attribute__((ext_vector_type(4)));
typedef short s16x8 __attribute__((ext_vector_type(8)));

#define VOCAB 256
#define EMB   128
#define HID   512
#define OUT_D 256
#define BATCH 64
#define SEQ   1024

__device__ __forceinline__ unsigned short f2bf(float f) {
  unsigned u = __builtin_bit_cast(unsigned, f);
  u += 0x7fffu + ((u >> 16) & 1u);
  return (unsigned short)(u >> 16);
}

// ---------------------------------------------------------------------------
// Prep 1: E2[v][c] = sum_e emb[v][e]*We[e][c] + bh[c]   (f32, 256x512)
// ---------------------------------------------------------------------------
__global__ void k_e2(const float* __restrict__ emb, const float* __restrict__ We,
                     const float* __restrict__ bh, float* __restrict__ E2)
{
  __shared__ float el[EMB];
  const int v = blockIdx.x, c = threadIdx.x;   // 512 threads
  if (c < EMB) el[c] = emb[v * EMB + c];
  __syncthreads();
  float s = bh[c];
  #pragma unroll
  for (int e = 0; e < EMB; ++e) s += el[e] * We[e * HID + c];
  E2[v * HID + c] = s;
}

// ---------------------------------------------------------------------------
// Prep 2: W_h -> int8 (x2048) packed as MFMA B-fragments for 16x16x64 i8.
// ---------------------------------------------------------------------------
__global__ void k_whfrag(const float* __restrict__ Wh, i32x4* __restrict__ WhF)
{
  const int g = blockIdx.x * 256 + threadIdx.x;   // 0..16383
  const int lane = g & 63, frag = g >> 6;         // frag 0..255
  const int kt = frag & 7, nt = (frag >> 3) & 3, w = frag >> 5;
  const int col = (w << 6) + (nt << 4) + (lane & 15);
  const int kb  = (kt << 6) + ((lane >> 4) << 4);
  int wd[4];
  #pragma unroll
  for (int q = 0; q < 4; ++q) {
    int b[4];
    #pragma unroll
    for (int j = 0; j < 4; ++j) {
      float s = Wh[(kb + q * 4 + j) * HID + col] * 2048.f;
      s = fminf(fmaxf(s, -127.f), 127.f);
      b[j] = __float2int_rn(s) & 255;
    }
    wd[q] = b[0] | (b[1] << 8) | (b[2] << 16) | (b[3] << 24);
  }
  i32x4 v = {wd[0], wd[1], wd[2], wd[3]};
  WhF[g] = v;
}

// ---------------------------------------------------------------------------
// Prep 3: W_o -> bf16 transposed AND pre-scaled by 1/127 (hist is int8 x127):
// WoT[col][k] = bf16(Wo[k][col] / 127)
// ---------------------------------------------------------------------------
__global__ void k_wot(const float* __restrict__ Wo, unsigned short* __restrict__ WoT)
{
  const int k = blockIdx.x;      // 512
  const int c = threadIdx.x;     // 256
  WoT[c * HID + k] = f2bf(Wo[k * OUT_D + c] * (1.0f / 127.0f));
}

// ---------------------------------------------------------------------------
// Scan: 64 WGs x 512 thr; ONE batch row per WG (fully independent recurrence).
// A-operand built by replicating the single h row across all 16 MFMA rows:
// every lane then holds a valid copy of col (nt*16+lrow) for every nt, so
// lane picks nt = lhi via 3 cndmask selects -> exactly ONE tanh per lane.
// W_h int8 B-frags in registers; h int8 (512B) double-buffered in LDS;
// E2/x gathers software-pipelined; hist stores NONTEMPORAL so E2 stays
// L2-resident; raw s_barrier with lgkmcnt-only drain per step.
// ---------------------------------------------------------------------------
__global__ __launch_bounds__(512, 2) void k_scan(
    const int* __restrict__ x, const float* __restrict__ h0,
    const float* __restrict__ E2, const i32x4* __restrict__ WhF,
    char* __restrict__ hist, float* __restrict__ fh)
{
  __shared__ __align__(16) char hbuf[2][HID];   // 2 x 512B int8 h
  const int tid  = threadIdx.x;
  const int wv   = tid >> 6, lane = tid & 63;
  const int lrow = lane & 15, lhi = lane >> 4;
  const int row  = blockIdx.x;                   // batch row (0..63)
  const int col  = (wv << 6) + (lhi << 4) + lrow;  // this lane's hidden col

  // W_h B-fragments -> registers (4 nt x 8 kt per wave)
  i32x4 bfr[4][8];
  #pragma unroll
  for (int nt = 0; nt < 4; ++nt)
    #pragma unroll
    for (int kt = 0; kt < 8; ++kt)
      bfr[nt][kt] = WhF[((((wv << 2) + nt) << 3) + kt) * 64 + lane];

  // h0 -> int8 into hbuf[0] (one byte per thread, linear layout)
  {
    float s = fminf(fmaxf(h0[(row << 9) + tid] * 127.f, -127.f), 127.f);
    hbuf[0][tid] = (char)__float2int_rn(s);
  }

  // prologue: hx(0) and id(1)
  const int id0 = x[(row << 10) + 0];
  int idA = x[(row << 10) + 1], idB;
  float hxA = E2[(id0 << 9) + col], hxB;
  __syncthreads();

  const float inv = 1.f / (127.f * 2048.f);
  const float TC  = 2.8853900817779268f;   // 2*log2(e)

#define STEP(T, PH, HXU, HXP, IDU, IDL)                                       \
  {                                                                           \
    const int t_ = (T);                                                       \
    /* history flush read: hbuf[PH] = outputs[t-1], stable this step */       \
    i32x4 fv;                                                                 \
    if (tid < 32) fv = *(const i32x4*)(&hbuf[PH][tid << 4]);                  \
    /* prefetch E2 value for t+1 (id fetched one step earlier) */             \
    HXP = E2[((IDU) << 9) + col];                                             \
    /* prefetch token id for t+2 */                                           \
    IDL = x[(row << 10) + ((t_ + 2 > SEQ - 1) ? SEQ - 1 : t_ + 2)];           \
    /* h_prev @ W_h : int8 MFMA (A rows replicated from the single h row) */  \
    i32x4 acc[4] = {};                                                        \
    _Pragma("unroll") for (int kt = 0; kt < 8; ++kt) {                        \
      i32x4 a = *(const i32x4*)(&hbuf[PH][(kt << 6) + (lhi << 4)]);           \
      _Pragma("unroll") for (int nt = 0; nt < 4; ++nt)                        \
        acc[nt] = __builtin_amdgcn_mfma_i32_16x16x64_i8(a, bfr[nt][kt],       \
                                                        acc[nt], 0, 0, 0);    \
    }                                                                         \
    /* nontemporal history store (keeps E2 resident in L2) */                 \
    if (t_ > 0 && tid < 32)                                                   \
      __builtin_nontemporal_store(fv, (i32x4*)(hist +                         \
          (((size_t)(row << 10) + (t_ - 1)) << 10) + (tid << 4)));            \
    /* select this lane's nt = lhi copy (all copies valid by replication) */  \
    int a01 = (lhi & 1) ? acc[1][0] : acc[0][0];                              \
    int a23 = (lhi & 1) ? acc[3][0] : acc[2][0];                              \
    int av  = (lhi & 2) ? a23 : a01;                                          \
    /* z = acc*inv + hx ; h = tanh(z) ; emit int8 */                          \
    float z = fmaf((float)av, inv, HXU);                                      \
    float e = __builtin_amdgcn_exp2f(z * TC);                                 \
    float h = fmaf(-2.f, __builtin_amdgcn_rcpf(1.f + e), 1.f);                \
    hbuf[1 - (PH)][col] = (char)__float2int_rn(h * 127.f);                    \
    if (t_ == SEQ - 1) fh[(row << 9) + col] = h;                              \
    asm volatile("s_waitcnt lgkmcnt(0)" ::: "memory");                        \
    __builtin_amdgcn_sched_barrier(0);                                        \
    __builtin_amdgcn_s_barrier();                                             \
    __builtin_amdgcn_sched_barrier(0);                                        \
  }

  for (int T2 = 0; T2 < SEQ / 2; ++T2) {
    STEP(2 * T2,     0, hxA, hxB, idA, idB)
    STEP(2 * T2 + 1, 1, hxB, hxA, idB, idA)
  }
#undef STEP

  // final flush: outputs[1023] lives in hbuf[0] (written by step 1023)
  if (tid < 32) {
    i32x4 fv = *(const i32x4*)(&hbuf[0][tid << 4]);
    __builtin_nontemporal_store(fv, (i32x4*)(hist +
        (((size_t)(row << 10) + (SEQ - 1)) << 10) + (tid << 4)));
  }
}

// ---------------------------------------------------------------------------
// Logits: A = int8 hist (512B prefix of each 1024B row slot) dequantized to
// bf16 during LDS staging (exact: |q|<=127 ints are exact bf16; 1/127 folded
// into WoT). GEMM in-place over d_out as before.
// ---------------------------------------------------------------------------
__global__ __launch_bounds__(256) void k_logits(const char* __restrict__ hist,
                                                const unsigned short* __restrict__ WoT,
                                                const float* __restrict__ bo, float* out)
{
  __shared__ __align__(16) char As[64 * 1024];
  const int tid = threadIdx.x;
  const int m0 = blockIdx.x * 64;

  // stage + dequant: 64 rows x 512 int8 -> bf16 tile with 16B-granule swizzle
  for (int i = tid; i < 1024; i += 256) {
    const int row = i >> 4, seg = i & 15;                 // 32 int8 cols/seg
    const char* src = hist + (size_t)(m0 + row) * 1024 + seg * 32;
    i32x4 w0 = *(const i32x4*)(src);
    i32x4 w1 = *(const i32x4*)(src + 16);
    unsigned od[16];
    #pragma unroll
    for (int d = 0; d < 8; ++d) {
      const unsigned dw = (unsigned)(d < 4 ? w0[d] : w1[d - 4]);
      const int q0 = (int)(signed char)(dw & 0xffu);
      const int q1 = (int)(signed char)((dw >> 8) & 0xffu);
      const int q2 = (int)(signed char)((dw >> 16) & 0xffu);
      const int q3 = (int)(signed char)(dw >> 24);
      const unsigned u0 = __builtin_bit_cast(unsigned, (float)q0);
      const unsigned u1 = __builtin_bit_cast(unsigned, (float)q1);
      const unsigned u2 = __builtin_bit_cast(unsigned, (float)q2);
      const unsigned u3 = __builtin_bit_cast(unsigned, (float)q3);
      od[2 * d]     = (u0 >> 16) | (u1 & 0xffff0000u);
      od[2 * d + 1] = (u2 >> 16) | (u3 & 0xffff0000u);
    }
    #pragma unroll
    for (int q = 0; q < 4; ++q) {
      i32x4 v = {(int)od[4 * q], (int)od[4 * q + 1],
                 (int)od[4 * q + 2], (int)od[4 * q + 3]};
      const int off = seg * 64 + q * 16;
      *(i32x4*)(&As[row * 1024 + (off ^ ((row & 7) << 4))]) = v;
    }
  }
  __syncthreads();

  const int wv = tid >> 6, lane = tid & 63, lrow = lane & 15, lhi = lane >> 4;
  const int cb = wv << 6;
  f32x4 acc[4][4] = {};
  #pragma unroll
  for (int kt = 0; kt < 16; ++kt) {
    s16x8 a[4], b[4];
    #pragma unroll
    for (int mt = 0; mt < 4; ++mt) {
      const int row = mt * 16 + lrow;
      a[mt] = *(const s16x8*)(&As[row * 1024 + ((kt * 64 + lhi * 16) ^ ((row & 7) << 4))]);
    }
    #pragma unroll
    for (int nt = 0; nt < 4; ++nt) {
      const int col = cb + nt * 16 + lrow;
      b[nt] = *(const s16x8*)((const char*)WoT + col * 1024 + kt * 64 + lhi * 16);
    }
    #pragma unroll
    for (int mt = 0; mt < 4; ++mt)
      #pragma unroll
      for (int nt = 0; nt < 4; ++nt)
        acc[mt][nt] = __builtin_amdgcn_mfma_f32_16x16x32_bf16(a[mt], b[nt], acc[mt][nt], 0, 0, 0);
  }
  #pragma unroll
  for (int nt = 0; nt < 4; ++nt) {
    const float bb = bo[cb + nt * 16 + lrow];
    #pragma unroll
    for (int mt = 0; mt < 4; ++mt)
      #pragma unroll
      for (int r = 0; r < 4; ++r)
        out[(size_t)(m0 + mt * 16 + lhi * 4 + r) * OUT_D + cb + nt * 16 + lrow] =
            acc[mt][nt][r] + bb;
  }
}

// ---------------------------------------------------------------------------
extern "C" void kernel_launch(void* const* d_in, const int* in_sizes, int n_in,
                              void* d_out, int out_size, void* d_ws, size_t ws_size,
                              hipStream_t stream)
{
  const int*   x   = (const int*)  d_in[0];
  const float* h0  = (const float*)d_in[1];
  const float* emb = (const float*)d_in[2];
  const float* We  = (const float*)d_in[3];
  const float* Wh  = (const float*)d_in[4];
  const float* bh  = (const float*)d_in[5];
  const float* Wo  = (const float*)d_in[6];
  const float* bo  = (const float*)d_in[7];
  float* out = (float*)d_out;
  char*  ws  = (char*)d_ws;

  float*          E2  = (float*)ws;                              // 512 KB
  i32x4*          WhF = (i32x4*)(ws + (512 << 10));              // 256 KB
  unsigned short* WoT = (unsigned short*)(ws + (768 << 10));     // 256 KB

  k_e2    <<<VOCAB, HID,   0, stream>>>(emb, We, bh, E2);
  k_whfrag<<<64,    256,   0, stream>>>(Wh, WhF);
  k_wot   <<<HID,   OUT_D, 0, stream>>>(Wo, WoT);

  // int8 h history lives in the 512B prefix of each logits row of d_out;
  // k_logits then overwrites each row in-place after staging it to LDS.
  k_scan  <<<BATCH, 512, 0, stream>>>(x, h0, E2, WhF,
                                      (char*)d_out,
                                      out + (size_t)BATCH * SEQ * OUT_D);
  k_logits<<<(BATCH * SEQ) / 64, 256, 0, stream>>>(
      (const char*)d_out, WoT, bo, out);
}

// Round 5
// 726.587 us; speedup vs baseline: 2.7148x; 1.0113x over previous
//
#include <hip/hip_runtime.h>

typedef float f32x4 __attribute__((ext_vector_type(4)));
typedef int   i32x4 __attribute__((ext_vector_type(4)));
typedef short s16x8 __attribute__((ext_vector_type(8)));

#define VOCAB 256
#define EMB   128
#define HID   512
#define OUT_D 256
#define BATCH 64
#define SEQ   1024

__device__ __forceinline__ unsigned short f2bf(float f) {
  unsigned u = __builtin_bit_cast(unsigned, f);
  u += 0x7fffu + ((u >> 16) & 1u);
  return (unsigned short)(u >> 16);
}

// ---------------------------------------------------------------------------
// Prep 1: E2[v][c] = sum_e emb[v][e]*We[e][c] + bh[c]   (f32, 256x512)
// ---------------------------------------------------------------------------
__global__ void k_e2(const float* __restrict__ emb, const float* __restrict__ We,
                     const float* __restrict__ bh, float* __restrict__ E2)
{
  __shared__ float el[EMB];
  const int v = blockIdx.x, c = threadIdx.x;   // 512 threads
  if (c < EMB) el[c] = emb[v * EMB + c];
  __syncthreads();
  float s = bh[c];
  #pragma unroll
  for (int e = 0; e < EMB; ++e) s += el[e] * We[e * HID + c];
  E2[v * HID + c] = s;
}

// ---------------------------------------------------------------------------
// Prep 2: W_h -> int8 (x2048) packed as MFMA B-fragments for 16x16x64 i8.
// frag = ct*8+kt (ct = coltile 0..31): lane holds B[k'][ct*16+(lane&15)],
// k' = kt*64 + (lane>>4)*16 + j
// ---------------------------------------------------------------------------
__global__ void k_whfrag(const float* __restrict__ Wh, i32x4* __restrict__ WhF)
{
  const int g = blockIdx.x * 256 + threadIdx.x;   // 0..16383
  const int lane = g & 63, frag = g >> 6;         // frag 0..255
  const int kt = frag & 7, ct = frag >> 3;        // ct 0..31
  const int col = (ct << 4) + (lane & 15);
  const int kb  = (kt << 6) + ((lane >> 4) << 4);
  int wd[4];
  #pragma unroll
  for (int q = 0; q < 4; ++q) {
    int b[4];
    #pragma unroll
    for (int j = 0; j < 4; ++j) {
      float s = Wh[(kb + q * 4 + j) * HID + col] * 2048.f;
      s = fminf(fmaxf(s, -127.f), 127.f);
      b[j] = __float2int_rn(s) & 255;
    }
    wd[q] = b[0] | (b[1] << 8) | (b[2] << 16) | (b[3] << 24);
  }
  i32x4 v = {wd[0], wd[1], wd[2], wd[3]};
  WhF[g] = v;
}

// ---------------------------------------------------------------------------
// Prep 3: W_o -> bf16 transposed AND pre-scaled by 1/127 (hist is int8 x127):
// WoT[col][k] = bf16(Wo[k][col] / 127)
// ---------------------------------------------------------------------------
__global__ void k_wot(const float* __restrict__ Wo, unsigned short* __restrict__ WoT)
{
  const int k = blockIdx.x;      // 512
  const int c = threadIdx.x;     // 256
  WoT[c * HID + k] = f2bf(Wo[k * OUT_D + c] * (1.0f / 127.0f));
}

// ---------------------------------------------------------------------------
// Scan: 64 WGs x 1024 thr (16 waves, 4/SIMD); ONE batch row per WG.
// A-operand replicates the single h row across all 16 MFMA rows; every lane
// holds a valid copy of each col, so lane picks its col with ONE cndmask.
// Each wave covers 32 cols (2 nt x 8 kt = 16 MFMAs); per-SIMD MFMA issue is
// the 64-MFMA floor, and the epilogue/barrier tail is 4-way wave-overlapped.
// ---------------------------------------------------------------------------
__global__ __launch_bounds__(1024, 4) void k_scan(
    const int* __restrict__ x, const float* __restrict__ h0,
    const float* __restrict__ E2, const i32x4* __restrict__ WhF,
    char* __restrict__ hist, float* __restrict__ fh)
{
  __shared__ __align__(16) char hbuf[2][HID];   // 2 x 512B int8 h
  const int tid  = threadIdx.x;
  const int wv   = tid >> 6, lane = tid & 63;
  const int lrow = lane & 15, lhi = lane >> 4;
  const int row  = blockIdx.x;                       // batch row (0..63)
  const int col  = (wv << 5) + ((lhi & 1) << 4) + lrow;  // this lane's col

  // W_h B-fragments -> registers (2 nt x 8 kt per wave; ct = wv*2+nt)
  i32x4 bfr[2][8];
  #pragma unroll
  for (int nt = 0; nt < 2; ++nt)
    #pragma unroll
    for (int kt = 0; kt < 8; ++kt)
      bfr[nt][kt] = WhF[((((wv << 1) + nt) << 3) + kt) * 64 + lane];

  // h0 -> int8 into hbuf[0] (one byte per thread, linear layout)
  if (tid < HID) {
    float s = fminf(fmaxf(h0[(row << 9) + tid] * 127.f, -127.f), 127.f);
    hbuf[0][tid] = (char)__float2int_rn(s);
  }

  // prologue: hx(0) and id(1)
  const int id0 = x[(row << 10) + 0];
  int idA = x[(row << 10) + 1], idB;
  float hxA = E2[(id0 << 9) + col], hxB;
  __syncthreads();

  const float inv = 1.f / (127.f * 2048.f);
  const float TC  = 2.8853900817779268f;   // 2*log2(e)

#define STEP(T, PH, HXU, HXP, IDU, IDL)                                       \
  {                                                                           \
    const int t_ = (T);                                                       \
    /* history flush read: hbuf[PH] = outputs[t-1], stable this step */       \
    i32x4 fv;                                                                 \
    if (tid < 32) fv = *(const i32x4*)(&hbuf[PH][tid << 4]);                  \
    /* prefetch E2 value for t+1 (id fetched one step earlier) */             \
    HXP = E2[((IDU) << 9) + col];                                             \
    /* prefetch token id for t+2 */                                           \
    IDL = x[(row << 10) + ((t_ + 2 > SEQ - 1) ? SEQ - 1 : t_ + 2)];           \
    /* h_prev @ W_h : int8 MFMA (A rows replicated from the single h row) */  \
    i32x4 acc[2] = {};                                                        \
    _Pragma("unroll") for (int kt = 0; kt < 8; ++kt) {                        \
      i32x4 a = *(const i32x4*)(&hbuf[PH][(kt << 6) + (lhi << 4)]);           \
      _Pragma("unroll") for (int nt = 0; nt < 2; ++nt)                        \
        acc[nt] = __builtin_amdgcn_mfma_i32_16x16x64_i8(a, bfr[nt][kt],       \
                                                        acc[nt], 0, 0, 0);    \
    }                                                                         \
    /* nontemporal history store (keeps E2 resident in L2) */                 \
    if (t_ > 0 && tid < 32)                                                   \
      __builtin_nontemporal_store(fv, (i32x4*)(hist +                         \
          (((size_t)(row << 10) + (t_ - 1)) << 10) + (tid << 4)));            \
    /* select this lane's nt = lhi&1 copy (all copies valid) */               \
    int av = (lhi & 1) ? acc[1][0] : acc[0][0];                               \
    /* z = acc*inv + hx ; h = tanh(z) ; emit int8 */                          \
    float z = fmaf((float)av, inv, HXU);                                      \
    float e = __builtin_amdgcn_exp2f(z * TC);                                 \
    float h = fmaf(-2.f, __builtin_amdgcn_rcpf(1.f + e), 1.f);                \
    hbuf[1 - (PH)][col] = (char)__float2int_rn(h * 127.f);                    \
    if (t_ == SEQ - 1) fh[(row << 9) + col] = h;                              \
    asm volatile("s_waitcnt lgkmcnt(0)" ::: "memory");                        \
    __builtin_amdgcn_sched_barrier(0);                                        \
    __builtin_amdgcn_s_barrier();                                             \
    __builtin_amdgcn_sched_barrier(0);                                        \
  }

  for (int T2 = 0; T2 < SEQ / 2; ++T2) {
    STEP(2 * T2,     0, hxA, hxB, idA, idB)
    STEP(2 * T2 + 1, 1, hxB, hxA, idB, idA)
  }
#undef STEP

  // final flush: outputs[1023] lives in hbuf[0] (written by step 1023)
  if (tid < 32) {
    i32x4 fv = *(const i32x4*)(&hbuf[0][tid << 4]);
    __builtin_nontemporal_store(fv, (i32x4*)(hist +
        (((size_t)(row << 10) + (SEQ - 1)) << 10) + (tid << 4)));
  }
}

// ---------------------------------------------------------------------------
// Logits: A = int8 hist (512B prefix of each 1024B row slot) dequantized to
// bf16 during LDS staging (exact: |q|<=127 ints are exact bf16; 1/127 folded
// into WoT). GEMM in-place over d_out as before.
// ---------------------------------------------------------------------------
__global__ __launch_bounds__(256) void k_logits(const char* __restrict__ hist,
                                                const unsigned short* __restrict__ WoT,
                                                const float* __restrict__ bo, float* out)
{
  __shared__ __align__(16) char As[64 * 1024];
  const int tid = threadIdx.x;
  const int m0 = blockIdx.x * 64;

  // stage + dequant: 64 rows x 512 int8 -> bf16 tile with 16B-granule swizzle
  for (int i = tid; i < 1024; i += 256) {
    const int row = i >> 4, seg = i & 15;                 // 32 int8 cols/seg
    const char* src = hist + (size_t)(m0 + row) * 1024 + seg * 32;
    i32x4 w0 = *(const i32x4*)(src);
    i32x4 w1 = *(const i32x4*)(src + 16);
    unsigned od[16];
    #pragma unroll
    for (int d = 0; d < 8; ++d) {
      const unsigned dw = (unsigned)(d < 4 ? w0[d] : w1[d - 4]);
      const int q0 = (int)(signed char)(dw & 0xffu);
      const int q1 = (int)(signed char)((dw >> 8) & 0xffu);
      const int q2 = (int)(signed char)((dw >> 16) & 0xffu);
      const int q3 = (int)(signed char)(dw >> 24);
      const unsigned u0 = __builtin_bit_cast(unsigned, (float)q0);
      const unsigned u1 = __builtin_bit_cast(unsigned, (float)q1);
      const unsigned u2 = __builtin_bit_cast(unsigned, (float)q2);
      const unsigned u3 = __builtin_bit_cast(unsigned, (float)q3);
      od[2 * d]     = (u0 >> 16) | (u1 & 0xffff0000u);
      od[2 * d + 1] = (u2 >> 16) | (u3 & 0xffff0000u);
    }
    #pragma unroll
    for (int q = 0; q < 4; ++q) {
      i32x4 v = {(int)od[4 * q], (int)od[4 * q + 1],
                 (int)od[4 * q + 2], (int)od[4 * q + 3]};
      const int off = seg * 64 + q * 16;
      *(i32x4*)(&As[row * 1024 + (off ^ ((row & 7) << 4))]) = v;
    }
  }
  __syncthreads();

  const int wv = tid >> 6, lane = tid & 63, lrow = lane & 15, lhi = lane >> 4;
  const int cb = wv << 6;
  f32x4 acc[4][4] = {};
  #pragma unroll
  for (int kt = 0; kt < 16; ++kt) {
    s16x8 a[4], b[4];
    #pragma unroll
    for (int mt = 0; mt < 4; ++mt) {
      const int row = mt * 16 + lrow;
      a[mt] = *(const s16x8*)(&As[row * 1024 + ((kt * 64 + lhi * 16) ^ ((row & 7) << 4))]);
    }
    #pragma unroll
    for (int nt = 0; nt < 4; ++nt) {
      const int col = cb + nt * 16 + lrow;
      b[nt] = *(const s16x8*)((const char*)WoT + col * 1024 + kt * 64 + lhi * 16);
    }
    #pragma unroll
    for (int mt = 0; mt < 4; ++mt)
      #pragma unroll
      for (int nt = 0; nt < 4; ++nt)
        acc[mt][nt] = __builtin_amdgcn_mfma_f32_16x16x32_bf16(a[mt], b[nt], acc[mt][nt], 0, 0, 0);
  }
  #pragma unroll
  for (int nt = 0; nt < 4; ++nt) {
    const float bb = bo[cb + nt * 16 + lrow];
    #pragma unroll
    for (int mt = 0; mt < 4; ++mt)
      #pragma unroll
      for (int r = 0; r < 4; ++r)
        out[(size_t)(m0 + mt * 16 + lhi * 4 + r) * OUT_D + cb + nt * 16 + lrow] =
            acc[mt][nt][r] + bb;
  }
}

// ---------------------------------------------------------------------------
extern "C" void kernel_launch(void* const* d_in, const int* in_sizes, int n_in,
                              void* d_out, int out_size, void* d_ws, size_t ws_size,
                              hipStream_t stream)
{
  const int*   x   = (const int*)  d_in[0];
  const float* h0  = (const float*)d_in[1];
  const float* emb = (const float*)d_in[2];
  const float* We  = (const float*)d_in[3];
  const float* Wh  = (const float*)d_in[4];
  const float* bh  = (const float*)d_in[5];
  const float* Wo  = (const float*)d_in[6];
  const float* bo  = (const float*)d_in[7];
  float* out = (float*)d_out;
  char*  ws  = (char*)d_ws;

  float*          E2  = (float*)ws;                              // 512 KB
  i32x4*          WhF = (i32x4*)(ws + (512 << 10));              // 256 KB
  unsigned short* WoT = (unsigned short*)(ws + (768 << 10));     // 256 KB

  k_e2    <<<VOCAB, HID,   0, stream>>>(emb, We, bh, E2);
  k_whfrag<<<64,    256,   0, stream>>>(Wh, WhF);
  k_wot   <<<HID,   OUT_D, 0, stream>>>(Wo, WoT);

  // int8 h history lives in the 512B prefix of each logits row of d_out;
  // k_logits then overwrites each row in-place after staging it to LDS.
  k_scan  <<<BATCH, 1024, 0, stream>>>(x, h0, E2, WhF,
                                       (char*)d_out,
                                       out + (size_t)BATCH * SEQ * OUT_D);
  k_logits<<<(BATCH * SEQ) / 64, 256, 0, stream>>>(
      (const char*)d_out, WoT, bo, out);
}

// Round 6
// 726.544 us; speedup vs baseline: 2.7150x; 1.0001x over previous
//
#include <hip/hip_runtime.h>

typedef float f32x4 __attribute__((ext_vector_type(4)));
typedef int   i32x4 __attribute__((ext_vector_type(4)));
typedef short s16x8 __attribute__((ext_vector_type(8)));

#define VOCAB 256
#define EMB   128
#define HID   512
#define OUT_D 256
#define BATCH 64
#define SEQ   1024

__device__ __forceinline__ unsigned short f2bf(float f) {
  unsigned u = __builtin_bit_cast(unsigned, f);
  u += 0x7fffu + ((u >> 16) & 1u);
  return (unsigned short)(u >> 16);
}

// ---------------------------------------------------------------------------
// Prep 1: E2[v][c] = sum_e emb[v][e]*We[e][c] + bh[c]   (f32, 256x512)
// ---------------------------------------------------------------------------
__global__ void k_e2(const float* __restrict__ emb, const float* __restrict__ We,
                     const float* __restrict__ bh, float* __restrict__ E2)
{
  __shared__ float el[EMB];
  const int v = blockIdx.x, c = threadIdx.x;   // 512 threads
  if (c < EMB) el[c] = emb[v * EMB + c];
  __syncthreads();
  float s = bh[c];
  #pragma unroll
  for (int e = 0; e < EMB; ++e) s += el[e] * We[e * HID + c];
  E2[v * HID + c] = s;
}

// ---------------------------------------------------------------------------
// Prep 2: W_h -> int8 (x2048) packed as MFMA B-fragments for 16x16x64 i8.
// frag = ct*8+kt (ct = coltile 0..31): lane holds B[k'][ct*16+(lane&15)],
// k' = kt*64 + (lane>>4)*16 + j
// ---------------------------------------------------------------------------
__global__ void k_whfrag(const float* __restrict__ Wh, i32x4* __restrict__ WhF)
{
  const int g = blockIdx.x * 256 + threadIdx.x;   // 0..16383
  const int lane = g & 63, frag = g >> 6;         // frag 0..255
  const int kt = frag & 7, ct = frag >> 3;        // ct 0..31
  const int col = (ct << 4) + (lane & 15);
  const int kb  = (kt << 6) + ((lane >> 4) << 4);
  int wd[4];
  #pragma unroll
  for (int q = 0; q < 4; ++q) {
    int b[4];
    #pragma unroll
    for (int j = 0; j < 4; ++j) {
      float s = Wh[(kb + q * 4 + j) * HID + col] * 2048.f;
      s = fminf(fmaxf(s, -127.f), 127.f);
      b[j] = __float2int_rn(s) & 255;
    }
    wd[q] = b[0] | (b[1] << 8) | (b[2] << 16) | (b[3] << 24);
  }
  i32x4 v = {wd[0], wd[1], wd[2], wd[3]};
  WhF[g] = v;
}

// ---------------------------------------------------------------------------
// Prep 2b: W_h rows 384..511 -> per-col packed dwords for VALU sdot4 path.
// Wv[col*32 + d] packs W[384+4d .. 384+4d+3][col] (int8 x2048), byte j = row j.
// ---------------------------------------------------------------------------
__global__ void k_wv(const float* __restrict__ Wh, int* __restrict__ Wv)
{
  const int g = blockIdx.x * 256 + threadIdx.x;   // 0..16383
  const int col = g >> 5, d = g & 31;
  const int k = 384 + d * 4;
  int b[4];
  #pragma unroll
  for (int j = 0; j < 4; ++j) {
    float s = Wh[(k + j) * HID + col] * 2048.f;
    s = fminf(fmaxf(s, -127.f), 127.f);
    b[j] = __float2int_rn(s) & 255;
  }
  Wv[(col << 5) + d] = b[0] | (b[1] << 8) | (b[2] << 16) | (b[3] << 24);
}

// ---------------------------------------------------------------------------
// Prep 3: W_o -> bf16 transposed AND pre-scaled by 1/127 (hist is int8 x127):
// WoT[col][k] = bf16(Wo[k][col] / 127)
// ---------------------------------------------------------------------------
__global__ void k_wot(const float* __restrict__ Wo, unsigned short* __restrict__ WoT)
{
  const int k = blockIdx.x;      // 512
  const int c = threadIdx.x;     // 256
  WoT[c * HID + k] = f2bf(Wo[k * OUT_D + c] * (1.0f / 127.0f));
}

// ---------------------------------------------------------------------------
// Scan: 64 WGs x 512 thr (8 waves, 2/SIMD); ONE batch row per WG.
// K-split: K 0..383 on the matrix pipe (4 nt x 6 kt MFMAs, A-rows replicated
// from the single h row; lane selects its col's copy with 3 cndmask), and
// K 384..511 on the VALU as 32 v_dot4_i32_i8 per lane for the lane's own col
// (weights resident in 32 VGPRs, h-slice via broadcast ds_read_b128).
// Per-CU MFMA/step drops 256 -> 192; the dot chain hides under MFMA issue.
// ---------------------------------------------------------------------------
__global__ __launch_bounds__(512, 2) void k_scan(
    const int* __restrict__ x, const float* __restrict__ h0,
    const float* __restrict__ E2, const i32x4* __restrict__ WhF,
    const int* __restrict__ Wv,
    char* __restrict__ hist, float* __restrict__ fh)
{
  __shared__ __align__(16) char hbuf[2][HID];   // 2 x 512B int8 h
  const int tid  = threadIdx.x;
  const int wv   = tid >> 6, lane = tid & 63;
  const int lrow = lane & 15, lhi = lane >> 4;
  const int row  = blockIdx.x;                       // batch row (0..63)
  const int col  = (wv << 6) + (lhi << 4) + lrow;    // this lane's hidden col

  // W_h B-fragments -> registers (4 nt x 6 kt per wave; ct = wv*4+nt)
  i32x4 bfr[4][6];
  #pragma unroll
  for (int nt = 0; nt < 4; ++nt)
    #pragma unroll
    for (int kt = 0; kt < 6; ++kt)
      bfr[nt][kt] = WhF[((((wv << 2) + nt) << 3) + kt) * 64 + lane];

  // VALU-path weights: K 384..511 for this lane's col (32 packed dwords)
  int wvr[32];
  #pragma unroll
  for (int d = 0; d < 32; ++d) wvr[d] = Wv[(col << 5) + d];

  // h0 -> int8 into hbuf[0] (one byte per thread, linear layout)
  {
    float s = fminf(fmaxf(h0[(row << 9) + tid] * 127.f, -127.f), 127.f);
    hbuf[0][tid] = (char)__float2int_rn(s);
  }

  // prologue: hx(0) and id(1)
  const int id0 = x[(row << 10) + 0];
  int idA = x[(row << 10) + 1], idB;
  float hxA = E2[(id0 << 9) + col], hxB;
  __syncthreads();

  const float inv = 1.f / (127.f * 2048.f);
  const float TC  = 2.8853900817779268f;   // 2*log2(e)

#define STEP(T, PH, HXU, HXP, IDU, IDL)                                       \
  {                                                                           \
    const int t_ = (T);                                                       \
    /* history flush read: hbuf[PH] = outputs[t-1], stable this step */       \
    i32x4 fv;                                                                 \
    if (tid < 32) fv = *(const i32x4*)(&hbuf[PH][tid << 4]);                  \
    /* prefetch E2 value for t+1 (id fetched one step earlier) */             \
    HXP = E2[((IDU) << 9) + col];                                             \
    /* prefetch token id for t+2 */                                           \
    IDL = x[(row << 10) + ((t_ + 2 > SEQ - 1) ? SEQ - 1 : t_ + 2)];           \
    /* VALU K-slice: dd = sum_{k=384..511} h[k]*W[k][col] (exact int8) */     \
    int dd = 0;                                                               \
    _Pragma("unroll") for (int q = 0; q < 8; ++q) {                           \
      i32x4 hq = *(const i32x4*)(&hbuf[PH][384 + (q << 4)]);                  \
      dd = __builtin_amdgcn_sdot4(hq[0], wvr[4 * q + 0], dd, false);          \
      dd = __builtin_amdgcn_sdot4(hq[1], wvr[4 * q + 1], dd, false);          \
      dd = __builtin_amdgcn_sdot4(hq[2], wvr[4 * q + 2], dd, false);          \
      dd = __builtin_amdgcn_sdot4(hq[3], wvr[4 * q + 3], dd, false);          \
    }                                                                         \
    /* matrix K-slice: K 0..383 (A rows replicated from the single h row) */  \
    i32x4 acc[4] = {};                                                        \
    _Pragma("unroll") for (int kt = 0; kt < 6; ++kt) {                        \
      i32x4 a = *(const i32x4*)(&hbuf[PH][(kt << 6) + (lhi << 4)]);           \
      _Pragma("unroll") for (int nt = 0; nt < 4; ++nt)                        \
        acc[nt] = __builtin_amdgcn_mfma_i32_16x16x64_i8(a, bfr[nt][kt],       \
                                                        acc[nt], 0, 0, 0);    \
    }                                                                         \
    /* nontemporal history store (keeps E2 resident in L2) */                 \
    if (t_ > 0 && tid < 32)                                                   \
      __builtin_nontemporal_store(fv, (i32x4*)(hist +                         \
          (((size_t)(row << 10) + (t_ - 1)) << 10) + (tid << 4)));            \
    /* select this lane's nt = lhi copy (all copies valid by replication) */  \
    int a01 = (lhi & 1) ? acc[1][0] : acc[0][0];                              \
    int a23 = (lhi & 1) ? acc[3][0] : acc[2][0];                              \
    int av  = (lhi & 2) ? a23 : a01;                                          \
    /* z = (mfma+dot)*inv + hx ; h = tanh(z) ; emit int8 */                   \
    float z = fmaf((float)(av + dd), inv, HXU);                               \
    float e = __builtin_amdgcn_exp2f(z * TC);                                 \
    float h = fmaf(-2.f, __builtin_amdgcn_rcpf(1.f + e), 1.f);                \
    hbuf[1 - (PH)][col] = (char)__float2int_rn(h * 127.f);                    \
    if (t_ == SEQ - 1) fh[(row << 9) + col] = h;                              \
    asm volatile("s_waitcnt lgkmcnt(0)" ::: "memory");                        \
    __builtin_amdgcn_sched_barrier(0);                                        \
    __builtin_amdgcn_s_barrier();                                             \
    __builtin_amdgcn_sched_barrier(0);                                        \
  }

  for (int T2 = 0; T2 < SEQ / 2; ++T2) {
    STEP(2 * T2,     0, hxA, hxB, idA, idB)
    STEP(2 * T2 + 1, 1, hxB, hxA, idB, idA)
  }
#undef STEP

  // final flush: outputs[1023] lives in hbuf[0] (written by step 1023)
  if (tid < 32) {
    i32x4 fv = *(const i32x4*)(&hbuf[0][tid << 4]);
    __builtin_nontemporal_store(fv, (i32x4*)(hist +
        (((size_t)(row << 10) + (SEQ - 1)) << 10) + (tid << 4)));
  }
}

// ---------------------------------------------------------------------------
// Logits: A = int8 hist (512B prefix of each 1024B row slot) dequantized to
// bf16 during LDS staging (exact: |q|<=127 ints are exact bf16; 1/127 folded
// into WoT). GEMM in-place over d_out as before.
// ---------------------------------------------------------------------------
__global__ __launch_bounds__(256) void k_logits(const char* __restrict__ hist,
                                                const unsigned short* __restrict__ WoT,
                                                const float* __restrict__ bo, float* out)
{
  __shared__ __align__(16) char As[64 * 1024];
  const int tid = threadIdx.x;
  const int m0 = blockIdx.x * 64;

  // stage + dequant: 64 rows x 512 int8 -> bf16 tile with 16B-granule swizzle
  for (int i = tid; i < 1024; i += 256) {
    const int row = i >> 4, seg = i & 15;                 // 32 int8 cols/seg
    const char* src = hist + (size_t)(m0 + row) * 1024 + seg * 32;
    i32x4 w0 = *(const i32x4*)(src);
    i32x4 w1 = *(const i32x4*)(src + 16);
    unsigned od[16];
    #pragma unroll
    for (int d = 0; d < 8; ++d) {
      const unsigned dw = (unsigned)(d < 4 ? w0[d] : w1[d - 4]);
      const int q0 = (int)(signed char)(dw & 0xffu);
      const int q1 = (int)(signed char)((dw >> 8) & 0xffu);
      const int q2 = (int)(signed char)((dw >> 16) & 0xffu);
      const int q3 = (int)(signed char)(dw >> 24);
      const unsigned u0 = __builtin_bit_cast(unsigned, (float)q0);
      const unsigned u1 = __builtin_bit_cast(unsigned, (float)q1);
      const unsigned u2 = __builtin_bit_cast(unsigned, (float)q2);
      const unsigned u3 = __builtin_bit_cast(unsigned, (float)q3);
      od[2 * d]     = (u0 >> 16) | (u1 & 0xffff0000u);
      od[2 * d + 1] = (u2 >> 16) | (u3 & 0xffff0000u);
    }
    #pragma unroll
    for (int q = 0; q < 4; ++q) {
      i32x4 v = {(int)od[4 * q], (int)od[4 * q + 1],
                 (int)od[4 * q + 2], (int)od[4 * q + 3]};
      const int off = seg * 64 + q * 16;
      *(i32x4*)(&As[row * 1024 + (off ^ ((row & 7) << 4))]) = v;
    }
  }
  __syncthreads();

  const int wv = tid >> 6, lane = tid & 63, lrow = lane & 15, lhi = lane >> 4;
  const int cb = wv << 6;
  f32x4 acc[4][4] = {};
  #pragma unroll
  for (int kt = 0; kt < 16; ++kt) {
    s16x8 a[4], b[4];
    #pragma unroll
    for (int mt = 0; mt < 4; ++mt) {
      const int row = mt * 16 + lrow;
      a[mt] = *(const s16x8*)(&As[row * 1024 + ((kt * 64 + lhi * 16) ^ ((row & 7) << 4))]);
    }
    #pragma unroll
    for (int nt = 0; nt < 4; ++nt) {
      const int col = cb + nt * 16 + lrow;
      b[nt] = *(const s16x8*)((const char*)WoT + col * 1024 + kt * 64 + lhi * 16);
    }
    #pragma unroll
    for (int mt = 0; mt < 4; ++mt)
      #pragma unroll
      for (int nt = 0; nt < 4; ++nt)
        acc[mt][nt] = __builtin_amdgcn_mfma_f32_16x16x32_bf16(a[mt], b[nt], acc[mt][nt], 0, 0, 0);
  }
  #pragma unroll
  for (int nt = 0; nt < 4; ++nt) {
    const float bb = bo[cb + nt * 16 + lrow];
    #pragma unroll
    for (int mt = 0; mt < 4; ++mt)
      #pragma unroll
      for (int r = 0; r < 4; ++r)
        out[(size_t)(m0 + mt * 16 + lhi * 4 + r) * OUT_D + cb + nt * 16 + lrow] =
            acc[mt][nt][r] + bb;
  }
}

// ---------------------------------------------------------------------------
extern "C" void kernel_launch(void* const* d_in, const int* in_sizes, int n_in,
                              void* d_out, int out_size, void* d_ws, size_t ws_size,
                              hipStream_t stream)
{
  const int*   x   = (const int*)  d_in[0];
  const float* h0  = (const float*)d_in[1];
  const float* emb = (const float*)d_in[2];
  const float* We  = (const float*)d_in[3];
  const float* Wh  = (const float*)d_in[4];
  const float* bh  = (const float*)d_in[5];
  const float* Wo  = (const float*)d_in[6];
  const float* bo  = (const float*)d_in[7];
  float* out = (float*)d_out;
  char*  ws  = (char*)d_ws;

  float*          E2  = (float*)ws;                              // 512 KB
  i32x4*          WhF = (i32x4*)(ws + (512 << 10));              // 256 KB
  unsigned short* WoT = (unsigned short*)(ws + (768 << 10));     // 256 KB
  int*            Wv  = (int*)(ws + (1024 << 10));               // 64 KB

  k_e2    <<<VOCAB, HID,   0, stream>>>(emb, We, bh, E2);
  k_whfrag<<<64,    256,   0, stream>>>(Wh, WhF);
  k_wv    <<<64,    256,   0, stream>>>(Wh, Wv);
  k_wot   <<<HID,   OUT_D, 0, stream>>>(Wo, WoT);

  // int8 h history lives in the 512B prefix of each logits row of d_out;
  // k_logits then overwrites each row in-place after staging it to LDS.
  k_scan  <<<BATCH, 512, 0, stream>>>(x, h0, E2, WhF, Wv,
                                      (char*)d_out,
                                      out + (size_t)BATCH * SEQ * OUT_D);
  k_logits<<<(BATCH * SEQ) / 64, 256, 0, stream>>>(
      (const char*)d_out, WoT, bo, out);
}